// Round 12
// baseline (363.577 us; speedup 1.0000x reference)
//
#include <hip/hip_runtime.h>
#include <hip/hip_bf16.h>

#define BD 2
#define HD 480
#define WD 480
#define CD 32
#define HALFD 16
#define WND 20
#define NP 500
#define PLANE (HD*WD)
#define TWO_PI_OVER_NP 0.012566370614359172954f  /* 2*pi/500 */

typedef __attribute__((ext_vector_type(8))) short bf16x8;
typedef __attribute__((ext_vector_type(4))) float f32x4;

__device__ __forceinline__ float gelu_f(float x) {
    return 0.5f * x * (1.0f + erff(x * 0.70710678118654752f));
}
__device__ __forceinline__ float bfbits2f(short s) {
    unsigned u = ((unsigned)(unsigned short)s) << 16;
    return __uint_as_float(u);
}
__device__ __forceinline__ short bf16s(float v) {
    __hip_bfloat16 b = __float2bfloat16(v);
    return *reinterpret_cast<short*>(&b);
}
__device__ __forceinline__ unsigned pk2(float a, float b) {
    return (unsigned)(unsigned short)bf16s(a) | ((unsigned)(unsigned short)bf16s(b) << 16);
}

// Fused input-MLPs + layer-0 F1. One block per (b,h) row (grid 960 x 512).
//   hidA -> A-pass MFMA -> sA -> coalesced A write
//   hidE -> E-pass MFMA -> scattered 8B E write + sA overwritten with G=A⊙E
//   F1 phase: pure-MFMA row-DFT of G (no per-element VALU product) -> Y1.
// v12: s_hid pitch 24 -> 16 (hidden vec is exactly 16 bf16). LDS 55.3 ->
// 47.6 KB => 3 blocks/CU (was 2; round-11 counters: occupancy 37.6%,
// latency-bound). Fragment reads become 4-way bank-aliased (1.58x on those
// ops) -- traded for +50% resident waves.
__global__ void __launch_bounds__(512) k_aeF1(
    const float* src, const float* inp,
    const float* iw1, const float* ib1,
    const float* iw2, const float* ib2,
    const float* ew1, const float* eb1,
    const float* ew2, const float* eb2,
    const __hip_bfloat16* Twig,
    __hip_bfloat16* A, __hip_bfloat16* E, __hip_bfloat16* Y1)
{
    __shared__ float s_iw1[80], s_ib1[16];
    __shared__ float s_ew1[48], s_eb1[16];
    __shared__ __align__(16) __hip_bfloat16 s_hid[480 * 16];  // hidden frags [px][16]
    __shared__ __align__(16) __hip_bfloat16 sA[32 * 488];     // A row, later G=A⊙E

    int tid = threadIdx.x;
    int lane = tid & 63, wv = tid >> 6;
    int c0 = lane & 15, kg = lane >> 4;
    int b = blockIdx.x / HD;
    int h = blockIdx.x % HD;

    if (tid < 80) s_iw1[tid] = iw1[tid];
    if (tid >= 96 && tid < 112) s_ib1[tid - 96] = ib1[tid - 96];
    if (tid >= 128 && tid < 176) s_ew1[tid - 128] = ew1[tid - 128];
    if (tid >= 192 && tid < 208) s_eb1[tid - 192] = eb1[tid - 192];

    // Second-layer weights as MFMA B-fragments, in registers (K=16 zero-pad to 32).
    bf16x8 bIn[2], bEps[2];
    float biasIn[2], biasEps[2];
    #pragma unroll
    for (int nt = 0; nt < 2; nt++) {
        int c = nt * 16 + c0;
        #pragma unroll
        for (int j = 0; j < 8; j++) {
            int k = kg * 8 + j;
            bIn[nt][j]  = (k < 16) ? bf16s(iw2[k * 32 + c]) : (short)0;
            bEps[nt][j] = (k < 16) ? bf16s(ew2[k * 32 + c]) : (short)0;
        }
        biasIn[nt]  = ib2[c];
        biasEps[nt] = eb2[c];
    }

    // feature inputs for pixel w = tid (< 480)
    float s0 = 0.f, s1 = 0.f, s2 = 0.f, xi = 0.f;
    float gx = (float)h * (1.0f / 479.0f);
    float gy = (float)tid * (1.0f / 479.0f);
    size_t pbase = (size_t)b * PLANE + (size_t)h * WD;
    if (tid < WD) {
        s0 = src[(pbase + tid) * 3 + 0];
        s1 = src[(pbase + tid) * 3 + 1];
        s2 = src[(pbase + tid) * 3 + 2];
        xi = inp[pbase + tid];
    }
    __syncthreads();

    // --- hidA ---
    if (tid < WD) {
        unsigned pk[8];
        #pragma unroll
        for (int j = 0; j < 16; j += 2) {
            float v0 = s_ib1[j]     + s0 * s_iw1[j]     + s1 * s_iw1[16 + j]
                     + s2 * s_iw1[32 + j]     + gx * s_iw1[48 + j]     + gy * s_iw1[64 + j];
            float v1 = s_ib1[j + 1] + s0 * s_iw1[j + 1] + s1 * s_iw1[16 + j + 1]
                     + s2 * s_iw1[32 + j + 1] + gx * s_iw1[48 + j + 1] + gy * s_iw1[64 + j + 1];
            pk[j >> 1] = pk2(gelu_f(v0), gelu_f(v1));
        }
        uint4* d = reinterpret_cast<uint4*>(&s_hid[tid * 16]);
        d[0] = make_uint4(pk[0], pk[1], pk[2], pk[3]);
        d[1] = make_uint4(pk[4], pk[5], pk[6], pk[7]);
    }
    __syncthreads();

    // --- A-pass MFMA: 60 tasks (30 tiles x 2 nt) -> sA ---
    for (int t = wv; t < 60; t += 8) {
        int tile = t >> 1, nt = t & 1;
        bf16x8 av = {0, 0, 0, 0, 0, 0, 0, 0};
        if (kg < 2)
            av = *reinterpret_cast<const bf16x8*>(&s_hid[(tile * 16 + c0) * 16 + kg * 8]);
        f32x4 acc = {0.f, 0.f, 0.f, 0.f};
        acc = __builtin_amdgcn_mfma_f32_16x16x32_bf16(av, bIn[nt], acc, 0, 0, 0);
        float bias = biasIn[nt];
        int ch = nt * 16 + c0;
        int px = tile * 16 + kg * 4;
        unsigned w0 = pk2(acc[0] + bias, acc[1] + bias);
        unsigned w1 = pk2(acc[2] + bias, acc[3] + bias);
        *reinterpret_cast<uint2*>(&sA[ch * 488 + px]) = make_uint2(w0, w1);
    }
    __syncthreads();

    // --- copy sA -> global A (coalesced uint4); hidE (s_hid overwrite is safe) ---
    {
        __hip_bfloat16* Adst = A + (size_t)b * CD * PLANE + (size_t)h * WD;
        for (int t = tid; t < 32 * 60; t += 512) {
            int row = t / 60, chunk = t % 60;
            uint4 v = *reinterpret_cast<const uint4*>(&sA[row * 488 + chunk * 8]);
            *reinterpret_cast<uint4*>(&Adst[(size_t)row * PLANE + chunk * 8]) = v;
        }
    }
    if (tid < WD) {
        unsigned pk[8];
        #pragma unroll
        for (int j = 0; j < 16; j += 2) {
            float v0 = s_eb1[j]     + xi * s_ew1[j]     + gx * s_ew1[16 + j]     + gy * s_ew1[32 + j];
            float v1 = s_eb1[j + 1] + xi * s_ew1[j + 1] + gx * s_ew1[16 + j + 1] + gy * s_ew1[32 + j + 1];
            pk[j >> 1] = pk2(gelu_f(v0), gelu_f(v1));
        }
        uint4* d = reinterpret_cast<uint4*>(&s_hid[tid * 16]);
        d[0] = make_uint4(pk[0], pk[1], pk[2], pk[3]);
        d[1] = make_uint4(pk[4], pk[5], pk[6], pk[7]);
    }
    __syncthreads();

    // --- E-pass MFMA: write E global (8B) + overwrite sA with G = A ⊙ E ---
    for (int t = wv; t < 60; t += 8) {
        int tile = t >> 1, nt = t & 1;
        bf16x8 av = {0, 0, 0, 0, 0, 0, 0, 0};
        if (kg < 2)
            av = *reinterpret_cast<const bf16x8*>(&s_hid[(tile * 16 + c0) * 16 + kg * 8]);
        f32x4 acc = {0.f, 0.f, 0.f, 0.f};
        acc = __builtin_amdgcn_mfma_f32_16x16x32_bf16(av, bEps[nt], acc, 0, 0, 0);
        float bias = biasEps[nt];
        int ch = nt * 16 + c0;
        int px = tile * 16 + kg * 4;
        float e0 = acc[0] + bias, e1 = acc[1] + bias;
        float e2 = acc[2] + bias, e3 = acc[3] + bias;
        *reinterpret_cast<uint2*>(&E[(size_t)(b * 32 + ch) * PLANE + (size_t)h * WD + px])
            = make_uint2(pk2(e0, e1), pk2(e2, e3));
        uint2 a8 = *reinterpret_cast<const uint2*>(&sA[ch * 488 + px]);
        float a0 = bfbits2f((short)(a8.x & 0xffff));
        float a1 = bfbits2f((short)(a8.x >> 16));
        float a2 = bfbits2f((short)(a8.y & 0xffff));
        float a3 = bfbits2f((short)(a8.y >> 16));
        *reinterpret_cast<uint2*>(&sA[ch * 488 + px])
            = make_uint2(pk2(a0 * e0, a1 * e1), pk2(a2 * e2, a3 * e3));
    }
    __syncthreads();

    // --- F1 phase: Y1(l=0) = row-DFT of G (pure MFMA), waves 0-5 ---
    if (wv < 6) {
        int mt = wv & 1, nt = wv >> 1;
        int c = mt * 16 + c0;
        const __hip_bfloat16* gbase = &sA[c * 488 + (kg << 3)];
        f32x4 acc = {0.f, 0.f, 0.f, 0.f};
        #pragma unroll
        for (int kt = 0; kt < 15; kt++) {
            bf16x8 gv = *reinterpret_cast<const bf16x8*>(gbase + kt * 32);
            bf16x8 bv = *reinterpret_cast<const bf16x8*>(Twig + (((kt * 3 + nt) << 9) + lane * 8));
            acc = __builtin_amdgcn_mfma_f32_16x16x32_bf16(gv, bv, acc, 0, 0, 0);
        }
        int n = nt * 16 + c0;
        if (n < 40) {
            int ky = n >> 1, part = n & 1;
            int crow = mt * 16 + (kg << 2);
            #pragma unroll
            for (int r = 0; r < 4; r++) {
                int cc = crow + r;
                Y1[((((size_t)(b * 32 + cc)) * WND + ky) * HD + h) * 2 + part] =
                    __float2bfloat16(acc[r]);
            }
        }
    }
}

// All four swizzled twiddle fragment tables in one kernel:
// Twig[0,45) | TinvF[45,105) | Tf2[105,255) | Ti1[255,435).
__global__ void k_tables(__hip_bfloat16* T) {
    int e = blockIdx.x * 256 + threadIdx.x;   // < 435*512
    if (e >= 435 * 512) return;
    int tile = e >> 9, r = e & 511;
    int lane = r >> 3, j = r & 7;
    float v = 0.0f;
    if (tile < 45) {                       // Twig: F1 row-DFT (K=480, N=48 pad)
        int kt = tile / 3, nt = tile % 3;
        int k = kt * 32 + ((lane >> 4) << 3) + j;
        int n = nt * 16 + (lane & 15);
        if (n < 40) {
            int ky = n >> 1;
            int idx = (k * ky) % NP;
            float ang = (float)idx * TWO_PI_OVER_NP;
            v = (n & 1) ? -sinf(ang) : cosf(ang);
        }
    } else if (tile < 105) {               // TinvF: I2 inverse-ky (K=64 pad, N=480)
        int t2 = tile - 45;
        int nt = t2 >> 1, kt = t2 & 1;
        int kk = kt * 32 + ((lane >> 4) << 3) + j;
        int w = nt * 16 + (lane & 15);
        if (kk < 40) {
            int ky = kk >> 1;
            int idx = (ky * w) % NP;
            float ang = (float)idx * TWO_PI_OVER_NP;
            v = (kk & 1) ? -sinf(ang) : cosf(ang);
        }
    } else if (tile < 255) {               // Tf2: F2 h-DFT (K=960, N=80)
        int t2 = tile - 105;
        int kt = t2 / 5, nt = t2 % 5;
        int k = kt * 32 + ((lane >> 4) << 3) + j;
        int n = nt * 16 + (lane & 15);
        int hh = k >> 1, ri = k & 1;
        int kxi = n >> 1, part = n & 1;
        int kx = (kxi < 20) ? kxi : kxi + 460;
        int idx = (kx * hh) % NP;
        float ang = (float)idx * TWO_PI_OVER_NP;
        float c = cosf(ang), s = sinf(ang);
        v = (part == 0) ? (ri == 0 ? c : s) : (ri == 0 ? -s : c);
    } else {                               // Ti1: I1 inverse-kx (K=96 pad, N=960)
        int t2 = tile - 255;
        int nt = t2 / 3, kt = t2 % 3;
        int k = kt * 32 + ((lane >> 4) << 3) + j;
        int n = nt * 16 + (lane & 15);
        if (k < 80) {
            int kxi = k >> 1, ri = k & 1;
            int hh = n >> 1, part = n & 1;
            int kx = (kxi < 20) ? kxi : kxi + 460;
            int idx = (kx * hh) % NP;
            float ang = (float)idx * TWO_PI_OVER_NP;
            float c = cosf(ang), s = sinf(ang);
            v = (part == 0) ? (ri == 0 ? c : -s) : (ri == 0 ? s : c);
        }
    }
    T[e] = __float2bfloat16(v);
}

// F2 as MFMA GEMM: M=1280 rows, K=960, N=80.
// 1 wave per block (grid 400): same 400 wave-tasks spread over all 256 CUs.
__global__ void __launch_bounds__(64) k_F2m(
    const __hip_bfloat16* Y1, const __hip_bfloat16* Tf2, float* Y2)
{
    int lane = threadIdx.x;
    int task = blockIdx.x;                   // < 400
    int mt = task / 5, nt = task % 5;
    int row = mt * 16 + (lane & 15);
    int koff = (lane >> 4) << 3;
    const __hip_bfloat16* arow = Y1 + (size_t)row * 960 + koff;
    f32x4 acc = {0.f, 0.f, 0.f, 0.f};
    #pragma unroll
    for (int kt = 0; kt < 30; kt++) {
        bf16x8 av = *reinterpret_cast<const bf16x8*>(arow + kt * 32);
        bf16x8 bv = *reinterpret_cast<const bf16x8*>(Tf2 + (((kt * 5 + nt) << 9) + lane * 8));
        acc = __builtin_amdgcn_mfma_f32_16x16x32_bf16(av, bv, acc, 0, 0, 0);
    }
    int n = nt * 16 + (lane & 15);
    int mb = mt * 16 + ((lane >> 4) << 2);
    #pragma unroll
    for (int r = 0; r < 4; r++)
        Y2[(size_t)(mb + r) * 80 + n] = acc[r];
}

// Channel mixing; writes Zb as bf16 rows [m][96] (cols 80..95 zero).
// Round-6 version (480 blocks x 256 thr): strided weight reads are
// L3-absorbed (6.55 MB/layer); round-8's 64-block variant regressed.
__global__ void __launch_bounds__(256) k_mix(
    const float* Y2, __hip_bfloat16* Zb,
    const float* fw1, const float* fw2, int l)
{
    int gid = blockIdx.x * 256 + threadIdx.x;  // < 122880
    int col = gid % 96;
    int row = gid / 96;
    if (col >= 80) { Zb[gid] = __float2bfloat16(0.0f); return; }
    int ky = row % 20;
    int oc = (row / 20) % 32;
    int b = row / 640;
    int z = col & 1;
    int kxi = col >> 1;
    const float* wp;
    int x;
    if (kxi < 20) { wp = fw1; x = kxi; } else { wp = fw2; x = kxi - 20; }
    size_t wbase = ((((size_t)(l * 32) * 32 + oc) * 20 + x) * 20 + ky) * 2 + z;
    const float* y2 = Y2 + ((size_t)b * 32 * 20 + ky) * 80 + kxi * 2 + z;
    float acc = 0.f;
    for (int i = 0; i < 32; i++) {
        float yv = y2[(size_t)i * 1600];
        float wv = wp[wbase + (size_t)i * 25600];
        acc += yv * wv;
    }
    Zb[gid] = __float2bfloat16(acc);
}

// I1 as MFMA GEMM: M=1280 rows, K=96 pad, N=960.
__global__ void __launch_bounds__(256) k_I1m(
    const __hip_bfloat16* Zb, const __hip_bfloat16* Ti1, __hip_bfloat16* U)
{
    int wv = threadIdx.x >> 6, lane = threadIdx.x & 63;
    int task = blockIdx.x * 4 + wv;          // < 4800
    int mt = task / 60, nt = task % 60;
    int row = mt * 16 + (lane & 15);
    int koff = (lane >> 4) << 3;
    const __hip_bfloat16* arow = Zb + (size_t)row * 96 + koff;
    f32x4 acc = {0.f, 0.f, 0.f, 0.f};
    #pragma unroll
    for (int kt = 0; kt < 3; kt++) {
        bf16x8 av = *reinterpret_cast<const bf16x8*>(arow + kt * 32);
        bf16x8 bv = *reinterpret_cast<const bf16x8*>(Ti1 + (((nt * 3 + kt) << 9) + lane * 8));
        acc = __builtin_amdgcn_mfma_f32_16x16x32_bf16(av, bv, acc, 0, 0, 0);
    }
    int n = nt * 16 + (lane & 15);
    int mb = mt * 16 + ((lane >> 4) << 2);
    #pragma unroll
    for (int r = 0; r < 4; r++)
        U[(size_t)(mb + r) * 960 + n] = __float2bfloat16(acc[r]);
}

// Fused I2(l) + F1(l+1), l = 0,1,2 (gelu always on).
// Copy pass wave-specialized onto waves 6,7 (idle during the 6-task F1
// phase) so waves 0-5 enter F1 MFMAs immediately after the barrier.
__global__ void __launch_bounds__(512) k_I2F1(
    const __hip_bfloat16* U, __hip_bfloat16* A,
    const __hip_bfloat16* E,
    const float* convw, const float* convb,
    const __hip_bfloat16* TinvF, const __hip_bfloat16* Twig,
    __hip_bfloat16* Y1, int l)
{
    __shared__ __align__(16) __hip_bfloat16 sUf[4 * 512];
    __shared__ __align__(16) __hip_bfloat16 sWf[2 * 512];
    __shared__ __align__(16) __hip_bfloat16 sA[32 * 488];   // new A row [oc][w]
    __shared__ float sB[CD];
    int tid = threadIdx.x;
    int b = blockIdx.x / HD;
    int h = blockIdx.x % HD;
    if (tid < CD) sB[tid] = convb[l * CD + tid];
    for (int t = tid; t < 2048; t += 512) {
        int j = t & 7, lane = (t >> 3) & 63, ktmt = t >> 9;
        int mt = ktmt >> 1, kt = ktmt & 1;
        int oc = mt * 16 + (lane & 15);
        int kk = kt * 32 + ((lane >> 4) << 3) + j;
        float v = 0.f;
        if (kk < 40) {
            int ky = kk >> 1;
            __hip_bfloat162 u = reinterpret_cast<const __hip_bfloat162*>(U)
                [(((size_t)b * CD + oc) * WND + ky) * HD + h];
            float sc = (ky == 0 ? 1.0f : 2.0f) * (1.0f / 250000.0f);
            v = ((kk & 1) ? __bfloat162float(u.y) : __bfloat162float(u.x)) * sc;
        }
        sUf[t] = __float2bfloat16(v);
    }
    for (int t = tid; t < 1024; t += 512) {
        int j = t & 7, lane = (t >> 3) & 63, mt = t >> 9;
        int oc = mt * 16 + (lane & 15);
        int ic = ((lane >> 4) << 3) + j;
        sWf[t] = __float2bfloat16(convw[(size_t)l * CD * CD + oc * CD + ic]);
    }
    __syncthreads();
    int wv = tid >> 6, lane = tid & 63;
    int c0 = lane & 15, kg = lane >> 4;
    const unsigned short* Ap = reinterpret_cast<const unsigned short*>(A)
        + (size_t)b * CD * PLANE + (size_t)h * WD;
    // --- I2 phase: Anew row -> LDS only (A_prev still intact in global) ---
    for (int t = wv; t < 60; t += 8) {
        int mt = t & 1, nt = t >> 1;
        f32x4 acc = {0.f, 0.f, 0.f, 0.f};
        #pragma unroll
        for (int kt = 0; kt < 2; kt++) {
            bf16x8 av = *reinterpret_cast<const bf16x8*>(&sUf[((mt * 2 + kt) << 9) + lane * 8]);
            bf16x8 bv = *reinterpret_cast<const bf16x8*>(TinvF + (((nt * 2 + kt) << 9) + lane * 8));
            acc = __builtin_amdgcn_mfma_f32_16x16x32_bf16(av, bv, acc, 0, 0, 0);
        }
        bf16x8 av2 = *reinterpret_cast<const bf16x8*>(&sWf[(mt << 9) + lane * 8]);
        bf16x8 bv2;
        #pragma unroll
        for (int j = 0; j < 8; j++)
            bv2[j] = (short)Ap[(size_t)(kg * 8 + j) * PLANE + nt * 16 + c0];
        acc = __builtin_amdgcn_mfma_f32_16x16x32_bf16(av2, bv2, acc, 0, 0, 0);
        int w = nt * 16 + c0;
        int ocb = mt * 16 + (kg << 2);
        #pragma unroll
        for (int r = 0; r < 4; r++) {
            short sv = bf16s(gelu_f(acc[r] + sB[ocb + r]));
            sA[(ocb + r) * 488 + w] = *reinterpret_cast<__hip_bfloat16*>(&sv);
        }
    }
    __syncthreads();
    if (wv < 6) {
        // --- F1 phase (waves 0-5, one task each): Y1(l+1) = row-DFT of (Anew ⊙ E) ---
        int mt = wv & 1, nt = wv >> 1;
        int c = mt * 16 + c0;
        const __hip_bfloat16* erow =
            E + ((size_t)(b * 32 + c)) * PLANE + (size_t)h * WD + (kg << 3);
        const __hip_bfloat16* albase = &sA[c * 488 + (kg << 3)];
        f32x4 acc = {0.f, 0.f, 0.f, 0.f};
        #pragma unroll
        for (int kt = 0; kt < 15; kt++) {
            bf16x8 av = *reinterpret_cast<const bf16x8*>(albase + kt * 32);
            bf16x8 ev = *reinterpret_cast<const bf16x8*>(erow + kt * 32);
            bf16x8 gv;
            #pragma unroll
            for (int j = 0; j < 8; j++)
                gv[j] = bf16s(bfbits2f(av[j]) * bfbits2f(ev[j]));
            bf16x8 bv = *reinterpret_cast<const bf16x8*>(Twig + (((kt * 3 + nt) << 9) + lane * 8));
            acc = __builtin_amdgcn_mfma_f32_16x16x32_bf16(gv, bv, acc, 0, 0, 0);
        }
        int n = nt * 16 + c0;
        if (n < 40) {
            int ky = n >> 1, part = n & 1;
            int crow = mt * 16 + (kg << 2);
            #pragma unroll
            for (int r = 0; r < 4; r++) {
                int cc = crow + r;
                Y1[((((size_t)(b * 32 + cc)) * WND + ky) * HD + h) * 2 + part] =
                    __float2bfloat16(acc[r]);
            }
        }
    } else {
        // --- copy pass (waves 6,7): sA -> global A (coalesced uint4) ---
        __hip_bfloat16* Adst = A + (size_t)b * CD * PLANE + (size_t)h * WD;
        for (int t = tid - 384; t < 32 * 60; t += 128) {
            int row = t / 60, chunk = t % 60;
            uint4 v = *reinterpret_cast<const uint4*>(&sA[row * 488 + chunk * 8]);
            *reinterpret_cast<uint4*>(&Adst[(size_t)row * PLANE + chunk * 8]) = v;
        }
    }
}

// Fused I2(l=3, no gelu) + final output.
// proj layer-1 (K=32, N=16) as MFMA; final A row stored [w][40] bf16;
// layer-2 (16->2) via 16-lane shfl_xor reduce into sP; mask-conv/combine
// pass unchanged.
__global__ void __launch_bounds__(512) k_I2out(
    const __hip_bfloat16* U, const __hip_bfloat16* A,
    const float* convw, const float* convb,
    const __hip_bfloat16* TinvF,
    const float* inp, const float* src,
    const float* pw1, const float* pb1,
    const float* pw2, const float* pb2,
    const float* mw, const float* mb,
    float* out, int l)
{
    __shared__ __align__(16) __hip_bfloat16 sUf[4 * 512];
    __shared__ __align__(16) __hip_bfloat16 sWf[2 * 512];
    __shared__ __align__(16) __hip_bfloat16 sAT[WD * 40];   // final A row [w][oc], pitch 40
    __shared__ float sP[WD * 2];                            // proj output per pixel
    __shared__ float sB[CD];
    __shared__ float sB1[HALFD], sW2[HALFD * 2], sB2[2], sM[9], sMB[1];
    int tid = threadIdx.x;
    int lane = tid & 63, wv = tid >> 6;
    int c0 = lane & 15, kg = lane >> 4;
    int b = blockIdx.x / HD;
    int h = blockIdx.x % HD;
    if (tid < CD) sB[tid] = convb[l * CD + tid];
    if (tid >= 32 && tid < 48) sB1[tid - 32] = pb1[tid - 32];
    if (tid >= 64 && tid < 96) sW2[tid - 64] = pw2[tid - 64];
    if (tid >= 96 && tid < 98) sB2[tid - 96] = pb2[tid - 96];
    if (tid >= 128 && tid < 137) sM[tid - 128] = mw[tid - 128];
    if (tid == 160) sMB[0] = mb[0];
    // proj layer-1 weights as register B-fragment: B[k][n], k=kg*8+j, n=c0 (K=32 exact)
    bf16x8 bW1;
    #pragma unroll
    for (int j = 0; j < 8; j++)
        bW1[j] = bf16s(pw1[(kg * 8 + j) * 16 + c0]);
    for (int t = tid; t < 2048; t += 512) {
        int j = t & 7, lane2 = (t >> 3) & 63, ktmt = t >> 9;
        int mt = ktmt >> 1, kt = ktmt & 1;
        int oc = mt * 16 + (lane2 & 15);
        int kk = kt * 32 + ((lane2 >> 4) << 3) + j;
        float v = 0.f;
        if (kk < 40) {
            int ky = kk >> 1;
            __hip_bfloat162 u = reinterpret_cast<const __hip_bfloat162*>(U)
                [(((size_t)b * CD + oc) * WND + ky) * HD + h];
            float sc = (ky == 0 ? 1.0f : 2.0f) * (1.0f / 250000.0f);
            v = ((kk & 1) ? __bfloat162float(u.y) : __bfloat162float(u.x)) * sc;
        }
        sUf[t] = __float2bfloat16(v);
    }
    for (int t = tid; t < 1024; t += 512) {
        int j = t & 7, lane2 = (t >> 3) & 63, mt = t >> 9;
        int oc = mt * 16 + (lane2 & 15);
        int ic = ((lane2 >> 4) << 3) + j;
        sWf[t] = __float2bfloat16(convw[(size_t)l * CD * CD + oc * CD + ic]);
    }
    __syncthreads();
    const unsigned short* Ap = reinterpret_cast<const unsigned short*>(A)
        + (size_t)b * CD * PLANE + (size_t)h * WD;
    // --- I2 phase (no gelu): final A row -> transposed LDS [w][40] ---
    for (int t = wv; t < 60; t += 8) {
        int mt = t & 1, nt = t >> 1;
        f32x4 acc = {0.f, 0.f, 0.f, 0.f};
        #pragma unroll
        for (int kt = 0; kt < 2; kt++) {
            bf16x8 av = *reinterpret_cast<const bf16x8*>(&sUf[((mt * 2 + kt) << 9) + lane * 8]);
            bf16x8 bv = *reinterpret_cast<const bf16x8*>(TinvF + (((nt * 2 + kt) << 9) + lane * 8));
            acc = __builtin_amdgcn_mfma_f32_16x16x32_bf16(av, bv, acc, 0, 0, 0);
        }
        bf16x8 av2 = *reinterpret_cast<const bf16x8*>(&sWf[(mt << 9) + lane * 8]);
        bf16x8 bv2;
        #pragma unroll
        for (int j = 0; j < 8; j++)
            bv2[j] = (short)Ap[(size_t)(kg * 8 + j) * PLANE + nt * 16 + c0];
        acc = __builtin_amdgcn_mfma_f32_16x16x32_bf16(av2, bv2, acc, 0, 0, 0);
        int w = nt * 16 + c0;
        int ocb = mt * 16 + (kg << 2);
        unsigned q0 = pk2(acc[0] + sB[ocb + 0], acc[1] + sB[ocb + 1]);
        unsigned q1 = pk2(acc[2] + sB[ocb + 2], acc[3] + sB[ocb + 3]);
        *reinterpret_cast<uint2*>(&sAT[w * 40 + ocb]) = make_uint2(q0, q1);
    }
    __syncthreads();
    // --- proj phase: layer-1 MFMA (30 tiles of 16 pixels), layer-2 shfl-reduce ---
    for (int t = wv; t < 30; t += 8) {
        bf16x8 av = *reinterpret_cast<const bf16x8*>(&sAT[(t * 16 + c0) * 40 + kg * 8]);
        f32x4 acc = {0.f, 0.f, 0.f, 0.f};
        acc = __builtin_amdgcn_mfma_f32_16x16x32_bf16(av, bW1, acc, 0, 0, 0);
        #pragma unroll
        for (int r = 0; r < 4; r++) {
            float hid = gelu_f(acc[r] + sB1[c0]);
            float p0 = hid * sW2[c0 * 2 + 0];
            float p1 = hid * sW2[c0 * 2 + 1];
            #pragma unroll
            for (int m = 1; m < 16; m <<= 1) {
                p0 += __shfl_xor(p0, m, 64);
                p1 += __shfl_xor(p1, m, 64);
            }
            if (c0 == 0) {
                int px = t * 16 + kg * 4 + r;
                sP[px * 2 + 0] = p0 + sB2[0];
                sP[px * 2 + 1] = p1 + sB2[1];
            }
        }
    }
    __syncthreads();
    // --- out phase: mask conv + combine, one thread per w ---
    for (int w = tid; w < WD; w += 512) {
        float p0 = sP[w * 2 + 0];
        float p1 = sP[w * 2 + 1];
        float m = sMB[0];
        #pragma unroll
        for (int dh = 0; dh < 3; dh++) {
            int hh = h + dh - 1;
            #pragma unroll
            for (int dw = 0; dw < 3; dw++) {
                int ww = w + dw - 1;
                if (hh >= 0 && hh < HD && ww >= 0 && ww < WD)
                    m += inp[(size_t)b * PLANE + (size_t)hh * WD + ww] * sM[dh * 3 + dw];
            }
        }
        size_t gid = (size_t)b * PLANE + (size_t)h * WD + w;
        float f0 = src[gid * 3 + 1];
        float f1 = src[gid * 3 + 2];
        out[gid * 2 + 0] = f0 * m + p0;
        out[gid * 2 + 1] = f1 * m + p1;
    }
}

extern "C" void kernel_launch(void* const* d_in, const int* in_sizes, int n_in,
                              void* d_out, int out_size, void* d_ws, size_t ws_size,
                              hipStream_t stream) {
    const float* inp = (const float*)d_in[0];
    const float* src = (const float*)d_in[1];
    const float* iw1 = (const float*)d_in[2];
    const float* ib1 = (const float*)d_in[3];
    const float* iw2 = (const float*)d_in[4];
    const float* ib2 = (const float*)d_in[5];
    const float* ew1 = (const float*)d_in[6];
    const float* eb1 = (const float*)d_in[7];
    const float* ew2 = (const float*)d_in[8];
    const float* eb2 = (const float*)d_in[9];
    const float* fw1 = (const float*)d_in[10];
    const float* fw2 = (const float*)d_in[11];
    const float* cw  = (const float*)d_in[12];
    const float* cb  = (const float*)d_in[13];
    const float* pw1 = (const float*)d_in[14];
    const float* pb1 = (const float*)d_in[15];
    const float* pw2 = (const float*)d_in[16];
    const float* pb2 = (const float*)d_in[17];
    const float* mw  = (const float*)d_in[18];
    const float* mb  = (const float*)d_in[19];

    // Workspace (~62.6 MB):
    //   A bf16 29.49 MB | E bf16 29.49 MB (layer-invariant e)
    //   | Y1U bf16 2.46 MB (Y1<->U aliased, identical layout) | Y2 f32 0.41 MB
    //   | Zb bf16 0.25 MB | tables bf16 435 tiles x 512 (Twig|TinvF|Tf2|Ti1)
    const size_t NA = (size_t)BD * CD * PLANE;
    __hip_bfloat16* A   = (__hip_bfloat16*)d_ws;
    __hip_bfloat16* E   = A + NA;
    __hip_bfloat16* Y1U = E + NA;
    float* Y2 = (float*)(Y1U + (size_t)BD * CD * WND * HD * 2);
    __hip_bfloat16* Zb = (__hip_bfloat16*)(Y2 + 1280 * 80);
    __hip_bfloat16* Tbl   = Zb + 1280 * 96;
    __hip_bfloat16* Twig  = Tbl;
    __hip_bfloat16* TinvF = Twig + 45 * 512;
    __hip_bfloat16* Tf2   = TinvF + 60 * 512;
    __hip_bfloat16* Ti1   = Tf2 + 150 * 512;

    k_tables<<<870, 256, 0, stream>>>(Tbl);
    // Fused input MLPs + layer-0 F1 (replaces k_ae + k_F1m).
    k_aeF1<<<BD * HD, 512, 0, stream>>>(src, inp, iw1, ib1, iw2, ib2,
                                        ew1, eb1, ew2, eb2, Twig, A, E, Y1U);
    for (int l = 0; l < 4; l++) {
        k_F2m<<<400, 64, 0, stream>>>(Y1U, Tf2, Y2);
        k_mix<<<480, 256, 0, stream>>>(Y2, Zb, fw1, fw2, l);
        k_I1m<<<1200, 256, 0, stream>>>(Zb, Ti1, Y1U);
        if (l < 3)
            k_I2F1<<<BD * HD, 512, 0, stream>>>(Y1U, A, E, cw, cb, TinvF, Twig,
                                                Y1U, l);
        else
            k_I2out<<<BD * HD, 512, 0, stream>>>(Y1U, A, cw, cb, TinvF,
                                                 inp, src, pw1, pb1, pw2, pb2,
                                                 mw, mb, (float*)d_out, l);
    }
}

// Round 13
// 348.954 us; speedup vs baseline: 1.0419x; 1.0419x over previous
//
#include <hip/hip_runtime.h>
#include <hip/hip_bf16.h>

#define BD 2
#define HD 480
#define WD 480
#define CD 32
#define HALFD 16
#define WND 20
#define NP 500
#define PLANE (HD*WD)
#define TWO_PI_OVER_NP 0.012566370614359172954f  /* 2*pi/500 */

typedef __attribute__((ext_vector_type(8))) short bf16x8;
typedef __attribute__((ext_vector_type(4))) float f32x4;

__device__ __forceinline__ float gelu_f(float x) {
    return 0.5f * x * (1.0f + erff(x * 0.70710678118654752f));
}
__device__ __forceinline__ float bfbits2f(short s) {
    unsigned u = ((unsigned)(unsigned short)s) << 16;
    return __uint_as_float(u);
}
__device__ __forceinline__ short bf16s(float v) {
    __hip_bfloat16 b = __float2bfloat16(v);
    return *reinterpret_cast<short*>(&b);
}
__device__ __forceinline__ unsigned pk2(float a, float b) {
    return (unsigned)(unsigned short)bf16s(a) | ((unsigned)(unsigned short)bf16s(b) << 16);
}
__device__ __forceinline__ unsigned mulpk(unsigned a, unsigned e) {
    return pk2(bfbits2f((short)(a & 0xffff)) * bfbits2f((short)(e & 0xffff)),
               bfbits2f((short)(a >> 16))    * bfbits2f((short)(e >> 16)));
}

// Fused input-MLPs + layer-0 F1. One block per (b,h) row (grid 960 x 512).
//   hidA -> A-pass MFMA -> sA -> coalesced A write
//   hidE -> E-pass MFMA -> scattered 8B E write + sA overwritten with G=A⊙E
//   F1 phase: pure-MFMA row-DFT of G (no per-element VALU product) -> Y1.
// s_hid pitch 16 (LDS 47.6 KB => 3 blocks/CU; round-12 counters: dur 76->50us).
__global__ void __launch_bounds__(512) k_aeF1(
    const float* src, const float* inp,
    const float* iw1, const float* ib1,
    const float* iw2, const float* ib2,
    const float* ew1, const float* eb1,
    const float* ew2, const float* eb2,
    const __hip_bfloat16* Twig,
    __hip_bfloat16* A, __hip_bfloat16* E, __hip_bfloat16* Y1)
{
    __shared__ float s_iw1[80], s_ib1[16];
    __shared__ float s_ew1[48], s_eb1[16];
    __shared__ __align__(16) __hip_bfloat16 s_hid[480 * 16];  // hidden frags [px][16]
    __shared__ __align__(16) __hip_bfloat16 sA[32 * 488];     // A row, later G=A⊙E

    int tid = threadIdx.x;
    int lane = tid & 63, wv = tid >> 6;
    int c0 = lane & 15, kg = lane >> 4;
    int b = blockIdx.x / HD;
    int h = blockIdx.x % HD;

    if (tid < 80) s_iw1[tid] = iw1[tid];
    if (tid >= 96 && tid < 112) s_ib1[tid - 96] = ib1[tid - 96];
    if (tid >= 128 && tid < 176) s_ew1[tid - 128] = ew1[tid - 128];
    if (tid >= 192 && tid < 208) s_eb1[tid - 192] = eb1[tid - 192];

    // Second-layer weights as MFMA B-fragments, in registers (K=16 zero-pad to 32).
    bf16x8 bIn[2], bEps[2];
    float biasIn[2], biasEps[2];
    #pragma unroll
    for (int nt = 0; nt < 2; nt++) {
        int c = nt * 16 + c0;
        #pragma unroll
        for (int j = 0; j < 8; j++) {
            int k = kg * 8 + j;
            bIn[nt][j]  = (k < 16) ? bf16s(iw2[k * 32 + c]) : (short)0;
            bEps[nt][j] = (k < 16) ? bf16s(ew2[k * 32 + c]) : (short)0;
        }
        biasIn[nt]  = ib2[c];
        biasEps[nt] = eb2[c];
    }

    // feature inputs for pixel w = tid (< 480)
    float s0 = 0.f, s1 = 0.f, s2 = 0.f, xi = 0.f;
    float gx = (float)h * (1.0f / 479.0f);
    float gy = (float)tid * (1.0f / 479.0f);
    size_t pbase = (size_t)b * PLANE + (size_t)h * WD;
    if (tid < WD) {
        s0 = src[(pbase + tid) * 3 + 0];
        s1 = src[(pbase + tid) * 3 + 1];
        s2 = src[(pbase + tid) * 3 + 2];
        xi = inp[pbase + tid];
    }
    __syncthreads();

    // --- hidA ---
    if (tid < WD) {
        unsigned pk[8];
        #pragma unroll
        for (int j = 0; j < 16; j += 2) {
            float v0 = s_ib1[j]     + s0 * s_iw1[j]     + s1 * s_iw1[16 + j]
                     + s2 * s_iw1[32 + j]     + gx * s_iw1[48 + j]     + gy * s_iw1[64 + j];
            float v1 = s_ib1[j + 1] + s0 * s_iw1[j + 1] + s1 * s_iw1[16 + j + 1]
                     + s2 * s_iw1[32 + j + 1] + gx * s_iw1[48 + j + 1] + gy * s_iw1[64 + j + 1];
            pk[j >> 1] = pk2(gelu_f(v0), gelu_f(v1));
        }
        uint4* d = reinterpret_cast<uint4*>(&s_hid[tid * 16]);
        d[0] = make_uint4(pk[0], pk[1], pk[2], pk[3]);
        d[1] = make_uint4(pk[4], pk[5], pk[6], pk[7]);
    }
    __syncthreads();

    // --- A-pass MFMA: 60 tasks (30 tiles x 2 nt) -> sA ---
    for (int t = wv; t < 60; t += 8) {
        int tile = t >> 1, nt = t & 1;
        bf16x8 av = {0, 0, 0, 0, 0, 0, 0, 0};
        if (kg < 2)
            av = *reinterpret_cast<const bf16x8*>(&s_hid[(tile * 16 + c0) * 16 + kg * 8]);
        f32x4 acc = {0.f, 0.f, 0.f, 0.f};
        acc = __builtin_amdgcn_mfma_f32_16x16x32_bf16(av, bIn[nt], acc, 0, 0, 0);
        float bias = biasIn[nt];
        int ch = nt * 16 + c0;
        int px = tile * 16 + kg * 4;
        unsigned w0 = pk2(acc[0] + bias, acc[1] + bias);
        unsigned w1 = pk2(acc[2] + bias, acc[3] + bias);
        *reinterpret_cast<uint2*>(&sA[ch * 488 + px]) = make_uint2(w0, w1);
    }
    __syncthreads();

    // --- copy sA -> global A (coalesced uint4); hidE (s_hid overwrite is safe) ---
    {
        __hip_bfloat16* Adst = A + (size_t)b * CD * PLANE + (size_t)h * WD;
        for (int t = tid; t < 32 * 60; t += 512) {
            int row = t / 60, chunk = t % 60;
            uint4 v = *reinterpret_cast<const uint4*>(&sA[row * 488 + chunk * 8]);
            *reinterpret_cast<uint4*>(&Adst[(size_t)row * PLANE + chunk * 8]) = v;
        }
    }
    if (tid < WD) {
        unsigned pk[8];
        #pragma unroll
        for (int j = 0; j < 16; j += 2) {
            float v0 = s_eb1[j]     + xi * s_ew1[j]     + gx * s_ew1[16 + j]     + gy * s_ew1[32 + j];
            float v1 = s_eb1[j + 1] + xi * s_ew1[j + 1] + gx * s_ew1[16 + j + 1] + gy * s_ew1[32 + j + 1];
            pk[j >> 1] = pk2(gelu_f(v0), gelu_f(v1));
        }
        uint4* d = reinterpret_cast<uint4*>(&s_hid[tid * 16]);
        d[0] = make_uint4(pk[0], pk[1], pk[2], pk[3]);
        d[1] = make_uint4(pk[4], pk[5], pk[6], pk[7]);
    }
    __syncthreads();

    // --- E-pass MFMA: write E global (8B) + overwrite sA with G = A ⊙ E ---
    for (int t = wv; t < 60; t += 8) {
        int tile = t >> 1, nt = t & 1;
        bf16x8 av = {0, 0, 0, 0, 0, 0, 0, 0};
        if (kg < 2)
            av = *reinterpret_cast<const bf16x8*>(&s_hid[(tile * 16 + c0) * 16 + kg * 8]);
        f32x4 acc = {0.f, 0.f, 0.f, 0.f};
        acc = __builtin_amdgcn_mfma_f32_16x16x32_bf16(av, bEps[nt], acc, 0, 0, 0);
        float bias = biasEps[nt];
        int ch = nt * 16 + c0;
        int px = tile * 16 + kg * 4;
        float e0 = acc[0] + bias, e1 = acc[1] + bias;
        float e2 = acc[2] + bias, e3 = acc[3] + bias;
        *reinterpret_cast<uint2*>(&E[(size_t)(b * 32 + ch) * PLANE + (size_t)h * WD + px])
            = make_uint2(pk2(e0, e1), pk2(e2, e3));
        uint2 a8 = *reinterpret_cast<const uint2*>(&sA[ch * 488 + px]);
        float a0 = bfbits2f((short)(a8.x & 0xffff));
        float a1 = bfbits2f((short)(a8.x >> 16));
        float a2 = bfbits2f((short)(a8.y & 0xffff));
        float a3 = bfbits2f((short)(a8.y >> 16));
        *reinterpret_cast<uint2*>(&sA[ch * 488 + px])
            = make_uint2(pk2(a0 * e0, a1 * e1), pk2(a2 * e2, a3 * e3));
    }
    __syncthreads();

    // --- F1 phase: Y1(l=0) = row-DFT of G (pure MFMA), waves 0-5 ---
    if (wv < 6) {
        int mt = wv & 1, nt = wv >> 1;
        int c = mt * 16 + c0;
        const __hip_bfloat16* gbase = &sA[c * 488 + (kg << 3)];
        f32x4 acc = {0.f, 0.f, 0.f, 0.f};
        #pragma unroll
        for (int kt = 0; kt < 15; kt++) {
            bf16x8 gv = *reinterpret_cast<const bf16x8*>(gbase + kt * 32);
            bf16x8 bv = *reinterpret_cast<const bf16x8*>(Twig + (((kt * 3 + nt) << 9) + lane * 8));
            acc = __builtin_amdgcn_mfma_f32_16x16x32_bf16(gv, bv, acc, 0, 0, 0);
        }
        int n = nt * 16 + c0;
        if (n < 40) {
            int ky = n >> 1, part = n & 1;
            int crow = mt * 16 + (kg << 2);
            #pragma unroll
            for (int r = 0; r < 4; r++) {
                int cc = crow + r;
                Y1[((((size_t)(b * 32 + cc)) * WND + ky) * HD + h) * 2 + part] =
                    __float2bfloat16(acc[r]);
            }
        }
    }
}

// All four swizzled twiddle fragment tables in one kernel:
// Twig[0,45) | TinvF[45,105) | Tf2[105,255) | Ti1[255,435).
__global__ void k_tables(__hip_bfloat16* T) {
    int e = blockIdx.x * 256 + threadIdx.x;   // < 435*512
    if (e >= 435 * 512) return;
    int tile = e >> 9, r = e & 511;
    int lane = r >> 3, j = r & 7;
    float v = 0.0f;
    if (tile < 45) {                       // Twig: F1 row-DFT (K=480, N=48 pad)
        int kt = tile / 3, nt = tile % 3;
        int k = kt * 32 + ((lane >> 4) << 3) + j;
        int n = nt * 16 + (lane & 15);
        if (n < 40) {
            int ky = n >> 1;
            int idx = (k * ky) % NP;
            float ang = (float)idx * TWO_PI_OVER_NP;
            v = (n & 1) ? -sinf(ang) : cosf(ang);
        }
    } else if (tile < 105) {               // TinvF: I2 inverse-ky (K=64 pad, N=480)
        int t2 = tile - 45;
        int nt = t2 >> 1, kt = t2 & 1;
        int kk = kt * 32 + ((lane >> 4) << 3) + j;
        int w = nt * 16 + (lane & 15);
        if (kk < 40) {
            int ky = kk >> 1;
            int idx = (ky * w) % NP;
            float ang = (float)idx * TWO_PI_OVER_NP;
            v = (kk & 1) ? -sinf(ang) : cosf(ang);
        }
    } else if (tile < 255) {               // Tf2: F2 h-DFT (K=960, N=80)
        int t2 = tile - 105;
        int kt = t2 / 5, nt = t2 % 5;
        int k = kt * 32 + ((lane >> 4) << 3) + j;
        int n = nt * 16 + (lane & 15);
        int hh = k >> 1, ri = k & 1;
        int kxi = n >> 1, part = n & 1;
        int kx = (kxi < 20) ? kxi : kxi + 460;
        int idx = (kx * hh) % NP;
        float ang = (float)idx * TWO_PI_OVER_NP;
        float c = cosf(ang), s = sinf(ang);
        v = (part == 0) ? (ri == 0 ? c : s) : (ri == 0 ? -s : c);
    } else {                               // Ti1: I1 inverse-kx (K=96 pad, N=960)
        int t2 = tile - 255;
        int nt = t2 / 3, kt = t2 % 3;
        int k = kt * 32 + ((lane >> 4) << 3) + j;
        int n = nt * 16 + (lane & 15);
        if (k < 80) {
            int kxi = k >> 1, ri = k & 1;
            int hh = n >> 1, part = n & 1;
            int kx = (kxi < 20) ? kxi : kxi + 460;
            int idx = (kx * hh) % NP;
            float ang = (float)idx * TWO_PI_OVER_NP;
            float c = cosf(ang), s = sinf(ang);
            v = (part == 0) ? (ri == 0 ? c : -s) : (ri == 0 ? s : c);
        }
    }
    T[e] = __float2bfloat16(v);
}

// F2 as MFMA GEMM: M=1280 rows, K=960, N=80.
// 1 wave per block (grid 400): same 400 wave-tasks spread over all 256 CUs.
__global__ void __launch_bounds__(64) k_F2m(
    const __hip_bfloat16* Y1, const __hip_bfloat16* Tf2, float* Y2)
{
    int lane = threadIdx.x;
    int task = blockIdx.x;                   // < 400
    int mt = task / 5, nt = task % 5;
    int row = mt * 16 + (lane & 15);
    int koff = (lane >> 4) << 3;
    const __hip_bfloat16* arow = Y1 + (size_t)row * 960 + koff;
    f32x4 acc = {0.f, 0.f, 0.f, 0.f};
    #pragma unroll
    for (int kt = 0; kt < 30; kt++) {
        bf16x8 av = *reinterpret_cast<const bf16x8*>(arow + kt * 32);
        bf16x8 bv = *reinterpret_cast<const bf16x8*>(Tf2 + (((kt * 5 + nt) << 9) + lane * 8));
        acc = __builtin_amdgcn_mfma_f32_16x16x32_bf16(av, bv, acc, 0, 0, 0);
    }
    int n = nt * 16 + (lane & 15);
    int mb = mt * 16 + ((lane >> 4) << 2);
    #pragma unroll
    for (int r = 0; r < 4; r++)
        Y2[(size_t)(mb + r) * 80 + n] = acc[r];
}

// Channel mixing; writes Zb as bf16 rows [m][96] (cols 80..95 zero).
// Round-6 version (480 blocks x 256 thr): strided weight reads are
// L3-absorbed (6.55 MB/layer); round-8's 64-block variant regressed.
__global__ void __launch_bounds__(256) k_mix(
    const float* Y2, __hip_bfloat16* Zb,
    const float* fw1, const float* fw2, int l)
{
    int gid = blockIdx.x * 256 + threadIdx.x;  // < 122880
    int col = gid % 96;
    int row = gid / 96;
    if (col >= 80) { Zb[gid] = __float2bfloat16(0.0f); return; }
    int ky = row % 20;
    int oc = (row / 20) % 32;
    int b = row / 640;
    int z = col & 1;
    int kxi = col >> 1;
    const float* wp;
    int x;
    if (kxi < 20) { wp = fw1; x = kxi; } else { wp = fw2; x = kxi - 20; }
    size_t wbase = ((((size_t)(l * 32) * 32 + oc) * 20 + x) * 20 + ky) * 2 + z;
    const float* y2 = Y2 + ((size_t)b * 32 * 20 + ky) * 80 + kxi * 2 + z;
    float acc = 0.f;
    for (int i = 0; i < 32; i++) {
        float yv = y2[(size_t)i * 1600];
        float wv = wp[wbase + (size_t)i * 25600];
        acc += yv * wv;
    }
    Zb[gid] = __float2bfloat16(acc);
}

// I1 as MFMA GEMM: M=1280 rows, K=96 pad, N=960.
__global__ void __launch_bounds__(256) k_I1m(
    const __hip_bfloat16* Zb, const __hip_bfloat16* Ti1, __hip_bfloat16* U)
{
    int wv = threadIdx.x >> 6, lane = threadIdx.x & 63;
    int task = blockIdx.x * 4 + wv;          // < 4800
    int mt = task / 60, nt = task % 60;
    int row = mt * 16 + (lane & 15);
    int koff = (lane >> 4) << 3;
    const __hip_bfloat16* arow = Zb + (size_t)row * 96 + koff;
    f32x4 acc = {0.f, 0.f, 0.f, 0.f};
    #pragma unroll
    for (int kt = 0; kt < 3; kt++) {
        bf16x8 av = *reinterpret_cast<const bf16x8*>(arow + kt * 32);
        bf16x8 bv = *reinterpret_cast<const bf16x8*>(Ti1 + (((nt * 3 + kt) << 9) + lane * 8));
        acc = __builtin_amdgcn_mfma_f32_16x16x32_bf16(av, bv, acc, 0, 0, 0);
    }
    int n = nt * 16 + (lane & 15);
    int mb = mt * 16 + ((lane >> 4) << 2);
    #pragma unroll
    for (int r = 0; r < 4; r++)
        U[(size_t)(mb + r) * 960 + n] = __float2bfloat16(acc[r]);
}

// Fused I2(l) + F1(l+1), l = 0,1,2 (gelu always on).
// v13: F1 phase made PURE MFMA (mirrors k_aeF1): the copy pass is extended
// to a fused {sA->A global, E global read (coalesced uint4), G=A⊙E -> sA}
// pass on all 8 waves, removing ~300 VALU repack inst + 15 global E loads
// from each F1 wave-task's critical chain.
__global__ void __launch_bounds__(512) k_I2F1(
    const __hip_bfloat16* U, __hip_bfloat16* A,
    const __hip_bfloat16* E,
    const float* convw, const float* convb,
    const __hip_bfloat16* TinvF, const __hip_bfloat16* Twig,
    __hip_bfloat16* Y1, int l)
{
    __shared__ __align__(16) __hip_bfloat16 sUf[4 * 512];
    __shared__ __align__(16) __hip_bfloat16 sWf[2 * 512];
    __shared__ __align__(16) __hip_bfloat16 sA[32 * 488];   // Anew row, later G=A⊙E
    __shared__ float sB[CD];
    int tid = threadIdx.x;
    int b = blockIdx.x / HD;
    int h = blockIdx.x % HD;
    if (tid < CD) sB[tid] = convb[l * CD + tid];
    for (int t = tid; t < 2048; t += 512) {
        int j = t & 7, lane = (t >> 3) & 63, ktmt = t >> 9;
        int mt = ktmt >> 1, kt = ktmt & 1;
        int oc = mt * 16 + (lane & 15);
        int kk = kt * 32 + ((lane >> 4) << 3) + j;
        float v = 0.f;
        if (kk < 40) {
            int ky = kk >> 1;
            __hip_bfloat162 u = reinterpret_cast<const __hip_bfloat162*>(U)
                [(((size_t)b * CD + oc) * WND + ky) * HD + h];
            float sc = (ky == 0 ? 1.0f : 2.0f) * (1.0f / 250000.0f);
            v = ((kk & 1) ? __bfloat162float(u.y) : __bfloat162float(u.x)) * sc;
        }
        sUf[t] = __float2bfloat16(v);
    }
    for (int t = tid; t < 1024; t += 512) {
        int j = t & 7, lane = (t >> 3) & 63, mt = t >> 9;
        int oc = mt * 16 + (lane & 15);
        int ic = ((lane >> 4) << 3) + j;
        sWf[t] = __float2bfloat16(convw[(size_t)l * CD * CD + oc * CD + ic]);
    }
    __syncthreads();
    int wv = tid >> 6, lane = tid & 63;
    int c0 = lane & 15, kg = lane >> 4;
    const unsigned short* Ap = reinterpret_cast<const unsigned short*>(A)
        + (size_t)b * CD * PLANE + (size_t)h * WD;
    // --- I2 phase: Anew row -> LDS only (A_prev still intact in global) ---
    for (int t = wv; t < 60; t += 8) {
        int mt = t & 1, nt = t >> 1;
        f32x4 acc = {0.f, 0.f, 0.f, 0.f};
        #pragma unroll
        for (int kt = 0; kt < 2; kt++) {
            bf16x8 av = *reinterpret_cast<const bf16x8*>(&sUf[((mt * 2 + kt) << 9) + lane * 8]);
            bf16x8 bv = *reinterpret_cast<const bf16x8*>(TinvF + (((nt * 2 + kt) << 9) + lane * 8));
            acc = __builtin_amdgcn_mfma_f32_16x16x32_bf16(av, bv, acc, 0, 0, 0);
        }
        bf16x8 av2 = *reinterpret_cast<const bf16x8*>(&sWf[(mt << 9) + lane * 8]);
        bf16x8 bv2;
        #pragma unroll
        for (int j = 0; j < 8; j++)
            bv2[j] = (short)Ap[(size_t)(kg * 8 + j) * PLANE + nt * 16 + c0];
        acc = __builtin_amdgcn_mfma_f32_16x16x32_bf16(av2, bv2, acc, 0, 0, 0);
        int w = nt * 16 + c0;
        int ocb = mt * 16 + (kg << 2);
        #pragma unroll
        for (int r = 0; r < 4; r++) {
            short sv = bf16s(gelu_f(acc[r] + sB[ocb + r]));
            sA[(ocb + r) * 488 + w] = *reinterpret_cast<__hip_bfloat16*>(&sv);
        }
    }
    __syncthreads();
    // --- fused pass (all 8 waves): sA -> global A; G = A⊙E -> sA ---
    {
        __hip_bfloat16* Adst = A + (size_t)b * CD * PLANE + (size_t)h * WD;
        const __hip_bfloat16* Erow = E + (size_t)b * CD * PLANE + (size_t)h * WD;
        for (int t = tid; t < 32 * 60; t += 512) {
            int row = t / 60, chunk = t % 60;
            uint4 a = *reinterpret_cast<const uint4*>(&sA[row * 488 + chunk * 8]);
            *reinterpret_cast<uint4*>(&Adst[(size_t)row * PLANE + chunk * 8]) = a;
            uint4 e = *reinterpret_cast<const uint4*>(&Erow[(size_t)row * PLANE + chunk * 8]);
            *reinterpret_cast<uint4*>(&sA[row * 488 + chunk * 8]) =
                make_uint4(mulpk(a.x, e.x), mulpk(a.y, e.y),
                           mulpk(a.z, e.z), mulpk(a.w, e.w));
        }
    }
    __syncthreads();
    // --- F1 phase: Y1(l+1) = row-DFT of G (pure MFMA), waves 0-5 ---
    if (wv < 6) {
        int mt = wv & 1, nt = wv >> 1;
        int c = mt * 16 + c0;
        const __hip_bfloat16* gbase = &sA[c * 488 + (kg << 3)];
        f32x4 acc = {0.f, 0.f, 0.f, 0.f};
        #pragma unroll
        for (int kt = 0; kt < 15; kt++) {
            bf16x8 gv = *reinterpret_cast<const bf16x8*>(gbase + kt * 32);
            bf16x8 bv = *reinterpret_cast<const bf16x8*>(Twig + (((kt * 3 + nt) << 9) + lane * 8));
            acc = __builtin_amdgcn_mfma_f32_16x16x32_bf16(gv, bv, acc, 0, 0, 0);
        }
        int n = nt * 16 + c0;
        if (n < 40) {
            int ky = n >> 1, part = n & 1;
            int crow = mt * 16 + (kg << 2);
            #pragma unroll
            for (int r = 0; r < 4; r++) {
                int cc = crow + r;
                Y1[((((size_t)(b * 32 + cc)) * WND + ky) * HD + h) * 2 + part] =
                    __float2bfloat16(acc[r]);
            }
        }
    }
}

// Fused I2(l=3, no gelu) + final output.
// proj layer-1 (K=32, N=16) as MFMA; final A row stored [w][40] bf16;
// layer-2 (16->2) via 16-lane shfl_xor reduce into sP; mask-conv/combine
// pass unchanged.
__global__ void __launch_bounds__(512) k_I2out(
    const __hip_bfloat16* U, const __hip_bfloat16* A,
    const float* convw, const float* convb,
    const __hip_bfloat16* TinvF,
    const float* inp, const float* src,
    const float* pw1, const float* pb1,
    const float* pw2, const float* pb2,
    const float* mw, const float* mb,
    float* out, int l)
{
    __shared__ __align__(16) __hip_bfloat16 sUf[4 * 512];
    __shared__ __align__(16) __hip_bfloat16 sWf[2 * 512];
    __shared__ __align__(16) __hip_bfloat16 sAT[WD * 40];   // final A row [w][oc], pitch 40
    __shared__ float sP[WD * 2];                            // proj output per pixel
    __shared__ float sB[CD];
    __shared__ float sB1[HALFD], sW2[HALFD * 2], sB2[2], sM[9], sMB[1];
    int tid = threadIdx.x;
    int lane = tid & 63, wv = tid >> 6;
    int c0 = lane & 15, kg = lane >> 4;
    int b = blockIdx.x / HD;
    int h = blockIdx.x % HD;
    if (tid < CD) sB[tid] = convb[l * CD + tid];
    if (tid >= 32 && tid < 48) sB1[tid - 32] = pb1[tid - 32];
    if (tid >= 64 && tid < 96) sW2[tid - 64] = pw2[tid - 64];
    if (tid >= 96 && tid < 98) sB2[tid - 96] = pb2[tid - 96];
    if (tid >= 128 && tid < 137) sM[tid - 128] = mw[tid - 128];
    if (tid == 160) sMB[0] = mb[0];
    // proj layer-1 weights as register B-fragment: B[k][n], k=kg*8+j, n=c0 (K=32 exact)
    bf16x8 bW1;
    #pragma unroll
    for (int j = 0; j < 8; j++)
        bW1[j] = bf16s(pw1[(kg * 8 + j) * 16 + c0]);
    for (int t = tid; t < 2048; t += 512) {
        int j = t & 7, lane2 = (t >> 3) & 63, ktmt = t >> 9;
        int mt = ktmt >> 1, kt = ktmt & 1;
        int oc = mt * 16 + (lane2 & 15);
        int kk = kt * 32 + ((lane2 >> 4) << 3) + j;
        float v = 0.f;
        if (kk < 40) {
            int ky = kk >> 1;
            __hip_bfloat162 u = reinterpret_cast<const __hip_bfloat162*>(U)
                [(((size_t)b * CD + oc) * WND + ky) * HD + h];
            float sc = (ky == 0 ? 1.0f : 2.0f) * (1.0f / 250000.0f);
            v = ((kk & 1) ? __bfloat162float(u.y) : __bfloat162float(u.x)) * sc;
        }
        sUf[t] = __float2bfloat16(v);
    }
    for (int t = tid; t < 1024; t += 512) {
        int j = t & 7, lane2 = (t >> 3) & 63, mt = t >> 9;
        int oc = mt * 16 + (lane2 & 15);
        int ic = ((lane2 >> 4) << 3) + j;
        sWf[t] = __float2bfloat16(convw[(size_t)l * CD * CD + oc * CD + ic]);
    }
    __syncthreads();
    const unsigned short* Ap = reinterpret_cast<const unsigned short*>(A)
        + (size_t)b * CD * PLANE + (size_t)h * WD;
    // --- I2 phase (no gelu): final A row -> transposed LDS [w][40] ---
    for (int t = wv; t < 60; t += 8) {
        int mt = t & 1, nt = t >> 1;
        f32x4 acc = {0.f, 0.f, 0.f, 0.f};
        #pragma unroll
        for (int kt = 0; kt < 2; kt++) {
            bf16x8 av = *reinterpret_cast<const bf16x8*>(&sUf[((mt * 2 + kt) << 9) + lane * 8]);
            bf16x8 bv = *reinterpret_cast<const bf16x8*>(TinvF + (((nt * 2 + kt) << 9) + lane * 8));
            acc = __builtin_amdgcn_mfma_f32_16x16x32_bf16(av, bv, acc, 0, 0, 0);
        }
        bf16x8 av2 = *reinterpret_cast<const bf16x8*>(&sWf[(mt << 9) + lane * 8]);
        bf16x8 bv2;
        #pragma unroll
        for (int j = 0; j < 8; j++)
            bv2[j] = (short)Ap[(size_t)(kg * 8 + j) * PLANE + nt * 16 + c0];
        acc = __builtin_amdgcn_mfma_f32_16x16x32_bf16(av2, bv2, acc, 0, 0, 0);
        int w = nt * 16 + c0;
        int ocb = mt * 16 + (kg << 2);
        unsigned q0 = pk2(acc[0] + sB[ocb + 0], acc[1] + sB[ocb + 1]);
        unsigned q1 = pk2(acc[2] + sB[ocb + 2], acc[3] + sB[ocb + 3]);
        *reinterpret_cast<uint2*>(&sAT[w * 40 + ocb]) = make_uint2(q0, q1);
    }
    __syncthreads();
    // --- proj phase: layer-1 MFMA (30 tiles of 16 pixels), layer-2 shfl-reduce ---
    for (int t = wv; t < 30; t += 8) {
        bf16x8 av = *reinterpret_cast<const bf16x8*>(&sAT[(t * 16 + c0) * 40 + kg * 8]);
        f32x4 acc = {0.f, 0.f, 0.f, 0.f};
        acc = __builtin_amdgcn_mfma_f32_16x16x32_bf16(av, bW1, acc, 0, 0, 0);
        #pragma unroll
        for (int r = 0; r < 4; r++) {
            float hid = gelu_f(acc[r] + sB1[c0]);
            float p0 = hid * sW2[c0 * 2 + 0];
            float p1 = hid * sW2[c0 * 2 + 1];
            #pragma unroll
            for (int m = 1; m < 16; m <<= 1) {
                p0 += __shfl_xor(p0, m, 64);
                p1 += __shfl_xor(p1, m, 64);
            }
            if (c0 == 0) {
                int px = t * 16 + kg * 4 + r;
                sP[px * 2 + 0] = p0 + sB2[0];
                sP[px * 2 + 1] = p1 + sB2[1];
            }
        }
    }
    __syncthreads();
    // --- out phase: mask conv + combine, one thread per w ---
    for (int w = tid; w < WD; w += 512) {
        float p0 = sP[w * 2 + 0];
        float p1 = sP[w * 2 + 1];
        float m = sMB[0];
        #pragma unroll
        for (int dh = 0; dh < 3; dh++) {
            int hh = h + dh - 1;
            #pragma unroll
            for (int dw = 0; dw < 3; dw++) {
                int ww = w + dw - 1;
                if (hh >= 0 && hh < HD && ww >= 0 && ww < WD)
                    m += inp[(size_t)b * PLANE + (size_t)hh * WD + ww] * sM[dh * 3 + dw];
            }
        }
        size_t gid = (size_t)b * PLANE + (size_t)h * WD + w;
        float f0 = src[gid * 3 + 1];
        float f1 = src[gid * 3 + 2];
        out[gid * 2 + 0] = f0 * m + p0;
        out[gid * 2 + 1] = f1 * m + p1;
    }
}

extern "C" void kernel_launch(void* const* d_in, const int* in_sizes, int n_in,
                              void* d_out, int out_size, void* d_ws, size_t ws_size,
                              hipStream_t stream) {
    const float* inp = (const float*)d_in[0];
    const float* src = (const float*)d_in[1];
    const float* iw1 = (const float*)d_in[2];
    const float* ib1 = (const float*)d_in[3];
    const float* iw2 = (const float*)d_in[4];
    const float* ib2 = (const float*)d_in[5];
    const float* ew1 = (const float*)d_in[6];
    const float* eb1 = (const float*)d_in[7];
    const float* ew2 = (const float*)d_in[8];
    const float* eb2 = (const float*)d_in[9];
    const float* fw1 = (const float*)d_in[10];
    const float* fw2 = (const float*)d_in[11];
    const float* cw  = (const float*)d_in[12];
    const float* cb  = (const float*)d_in[13];
    const float* pw1 = (const float*)d_in[14];
    const float* pb1 = (const float*)d_in[15];
    const float* pw2 = (const float*)d_in[16];
    const float* pb2 = (const float*)d_in[17];
    const float* mw  = (const float*)d_in[18];
    const float* mb  = (const float*)d_in[19];

    // Workspace (~62.6 MB):
    //   A bf16 29.49 MB | E bf16 29.49 MB (layer-invariant e)
    //   | Y1U bf16 2.46 MB (Y1<->U aliased, identical layout) | Y2 f32 0.41 MB
    //   | Zb bf16 0.25 MB | tables bf16 435 tiles x 512 (Twig|TinvF|Tf2|Ti1)
    const size_t NA = (size_t)BD * CD * PLANE;
    __hip_bfloat16* A   = (__hip_bfloat16*)d_ws;
    __hip_bfloat16* E   = A + NA;
    __hip_bfloat16* Y1U = E + NA;
    float* Y2 = (float*)(Y1U + (size_t)BD * CD * WND * HD * 2);
    __hip_bfloat16* Zb = (__hip_bfloat16*)(Y2 + 1280 * 80);
    __hip_bfloat16* Tbl   = Zb + 1280 * 96;
    __hip_bfloat16* Twig  = Tbl;
    __hip_bfloat16* TinvF = Twig + 45 * 512;
    __hip_bfloat16* Tf2   = TinvF + 60 * 512;
    __hip_bfloat16* Ti1   = Tf2 + 150 * 512;

    k_tables<<<870, 256, 0, stream>>>(Tbl);
    // Fused input MLPs + layer-0 F1 (replaces k_ae + k_F1m).
    k_aeF1<<<BD * HD, 512, 0, stream>>>(src, inp, iw1, ib1, iw2, ib2,
                                        ew1, eb1, ew2, eb2, Twig, A, E, Y1U);
    for (int l = 0; l < 4; l++) {
        k_F2m<<<400, 64, 0, stream>>>(Y1U, Tf2, Y2);
        k_mix<<<480, 256, 0, stream>>>(Y2, Zb, fw1, fw2, l);
        k_I1m<<<1200, 256, 0, stream>>>(Zb, Ti1, Y1U);
        if (l < 3)
            k_I2F1<<<BD * HD, 512, 0, stream>>>(Y1U, A, E, cw, cb, TinvF, Twig,
                                                Y1U, l);
        else
            k_I2out<<<BD * HD, 512, 0, stream>>>(Y1U, A, cw, cb, TinvF,
                                                 inp, src, pw1, pb1, pw2, pb2,
                                                 mw, mb, (float*)d_out, l);
    }
}